// Round 3
// baseline (755.646 us; speedup 1.0000x reference)
//
#include <hip/hip_runtime.h>
#include <hip/hip_bf16.h>
#include <stdint.h>

#define B_ 32
#define T_ 2048
#define D_ 1024
#define N_ 1024
#define M_ (B_*T_)

// k2 geometry
#define BM 128
#define BN 256
#define BK 32
#define NSTEP 128          // 4 nt-passes * 32 k-steps
#define BUFBYTES 49152     // Af 16K (f32) + Bh 16K + Bl 16K
#define AF_OFF 0
#define BH_OFF 16384
#define BL_OFF 32768
#define SMEM_TOTAL (3 * BUFBYTES)

typedef short bf16x8 __attribute__((ext_vector_type(8)));
typedef float f32x4 __attribute__((ext_vector_type(4)));

__device__ __forceinline__ unsigned short bf16_rn(float x) {
    unsigned u = __float_as_uint(x);
    u += 0x7FFFu + ((u >> 16) & 1u);
    return (unsigned short)(u >> 16);
}

__device__ __forceinline__ void gload_lds16(const void* g, void* l) {
    __builtin_amdgcn_global_load_lds(
        (__attribute__((address_space(1))) void*)(g),
        (__attribute__((address_space(3))) void*)(l), 16, 0, 0);
}

#define FENCE() asm volatile("" ::: "memory")
#define BARRIER() do { FENCE(); __builtin_amdgcn_s_barrier(); FENCE(); } while (0)

// K0: W2 [D][N] fp32 -> W2T hi/lo bf16 [N][D]
__global__ void k0_w2t(const float* __restrict__ W2,
                       unsigned short* __restrict__ Th,
                       unsigned short* __restrict__ Tl) {
    __shared__ float tile[32][33];
    int n0 = blockIdx.x * 32, d0 = blockIdx.y * 32;
    int tx = threadIdx.x & 31, ty = threadIdx.x >> 5; // 32 x 8
    #pragma unroll
    for (int i = 0; i < 4; i++) {
        int d = d0 + ty + i * 8;
        tile[ty + i * 8][tx] = W2[d * N_ + n0 + tx];
    }
    __syncthreads();
    #pragma unroll
    for (int i = 0; i < 4; i++) {
        int n = n0 + ty + i * 8;
        float v = tile[tx][ty + i * 8];
        unsigned short h = bf16_rn(v);
        float hf = __uint_as_float((unsigned)h << 16);
        unsigned short l = bf16_rn(v - hf);
        Th[n * D_ + d0 + tx] = h;
        Tl[n * D_ + d0 + tx] = l;
    }
}

// K1: q_proj[b][n] = query[b]@W1[:,n] + b1[n]   (fp32)
__global__ void k1_qproj(const float* __restrict__ query,
                         const float* __restrict__ W1,
                         const float* __restrict__ b1,
                         float* __restrict__ qp) {
    int b = blockIdx.x;
    int n = blockIdx.y * 256 + threadIdx.x;
    const float* q = query + b * D_;
    const float* w = W1 + n;
    float s = 0.f;
    #pragma unroll 8
    for (int d = 0; d < D_; d++) s += q[d] * w[d * N_];
    qp[b * N_ + n] = s + b1[n];
}

// --- k2 staging helpers (all LDS writes via global_load_lds; vmcnt-accounted)
// A tile: [g][128 rows][8 f32] per buffer; 2 instr/thread
__device__ __forceinline__ void stage_A(char* buf, int u, int m0, int w, int lane,
                                        const float* __restrict__ values) {
    const int k0 = (u & 31) * BK;
    #pragma unroll
    for (int i = 0; i < 2; i++) {
        int c = (w + i * 8) * 64 + lane;     // 0..1023 chunk id
        int g = c >> 8;                      // k-group
        int row = (c & 255) >> 1;
        int half = c & 1;
        const float* src = values + (size_t)(m0 + row) * D_ + k0 + g * 8 + half * 4;
        char* dst = buf + AF_OFF + (w + i * 8) * 1024;   // wave-uniform base
        gload_lds16(src, dst);
    }
}
// B tile: [g][256 rows][8 bf16] per buffer; 2 instr/thread per (hi|lo)
__device__ __forceinline__ void stage_B(char* buf, int off, int u, int w, int lane,
                                        const unsigned short* __restrict__ W) {
    const int k0 = (u & 31) * BK;
    const int nt = u >> 5;
    #pragma unroll
    for (int i = 0; i < 2; i++) {
        int c = (w + i * 8) * 64 + lane;
        int g = c >> 8;
        int row = c & 255;
        const unsigned short* src = W + (size_t)(nt * BN + row) * D_ + k0 + g * 8;
        char* dst = buf + off + (w + i * 8) * 1024;
        gload_lds16(src, dst);
    }
}

__device__ __forceinline__ void cvt_hilo(float4 a, float4 b, bf16x8& h, bf16x8& l) {
    float f[8] = {a.x, a.y, a.z, a.w, b.x, b.y, b.z, b.w};
    #pragma unroll
    for (int i = 0; i < 8; i++) {
        unsigned u = __float_as_uint(f[i]);
        unsigned uh = u + 0x7FFFu + ((u >> 16) & 1u);
        unsigned short hs = (unsigned short)(uh >> 16);
        float hf = __uint_as_float((unsigned)hs << 16);
        float r = f[i] - hf;
        unsigned ur = __float_as_uint(r);
        unsigned ul = ur + 0x7FFFu + ((ur >> 16) & 1u);
        h[i] = (short)hs;
        l[i] = (short)(ul >> 16);
    }
}

#define MFMA3(ah, al, bh, bl, A) do { \
    (A) = __builtin_amdgcn_mfma_f32_16x16x32_bf16((ah), (bh), (A), 0, 0, 0); \
    (A) = __builtin_amdgcn_mfma_f32_16x16x32_bf16((ah), (bl), (A), 0, 0, 0); \
    (A) = __builtin_amdgcn_mfma_f32_16x16x32_bf16((al), (bh), (A), 0, 0, 0); \
} while (0)

// K2: fused score GEMM, counted-vmcnt 4-phase schedule, triple-buffered LDS.
__global__ __launch_bounds__(512, 2) void k2_score(
    const float* __restrict__ values,
    const unsigned short* __restrict__ W2Th,
    const unsigned short* __restrict__ W2Tl,
    const float* __restrict__ qp,
    const float* __restrict__ b2,
    const float* __restrict__ V,
    const float* __restrict__ bV,
    float* __restrict__ score) {
    extern __shared__ char smem[];

    const int tid = threadIdx.x;
    const int lane = tid & 63;
    const int w = tid >> 6;       // 0..7
    const int wm = w >> 2;        // 0..1  (M waves)
    const int wn = w & 3;         // 0..3  (N waves)
    const int c16 = lane & 15;
    const int g = lane >> 4;      // 0..3 k-group
    const int m0 = blockIdx.x * BM;
    const int b = m0 >> 11;       // m0 / T_

    f32x4 acc[4][4];
    #pragma unroll
    for (int mi = 0; mi < 4; mi++)
        #pragma unroll
        for (int ni = 0; ni < 4; ni++) {
            f32x4 z = {0.f, 0.f, 0.f, 0.f};
            acc[mi][ni] = z;
        }
    float rowpart[16];
    #pragma unroll
    for (int i = 0; i < 16; i++) rowpart[i] = 0.f;

    // prologue: stage steps 0 and 1 (6 loads/thread each, order A,Bh,Bl)
    {
        char* b0 = smem;
        char* b1 = smem + BUFBYTES;
        stage_A(b0, 0, m0, w, lane, values);
        stage_B(b0, BH_OFF, 0, w, lane, W2Th);
        stage_B(b0, BL_OFF, 0, w, lane, W2Tl);
        stage_A(b1, 1, m0, w, lane, values);
        stage_B(b1, BH_OFF, 1, w, lane, W2Th);
        stage_B(b1, BL_OFF, 1, w, lane, W2Tl);
    }
    asm volatile("s_waitcnt vmcnt(6)" ::: "memory"); // buf0 landed (6 for buf1 in flight)
    BARRIER();                                       // all waves' slices landed

    for (int s = 0; s < NSTEP; ++s) {
        char* buf  = smem + (s % 3) * BUFBYTES;
        char* bufn = smem + ((s + 2) % 3) * BUFBYTES;
        const bool do_stage = (s + 2) < NSTEP;

        const char* aP  = buf + AF_OFF + g * 4096 + (wm * 64 + c16) * 32; // mi stride 512B
        const char* bhP = buf + BH_OFF + g * 4096 + (wn * 64 + c16) * 16; // ni stride 256B
        const char* blP = buf + BL_OFF + g * 4096 + (wn * 64 + c16) * 16;

        // ---------- phase 0: read A01 + B01, stage A(s+2), MFMA 01x01
        float4 a0x = *(const float4*)(aP);
        float4 a0y = *(const float4*)(aP + 16);
        float4 a1x = *(const float4*)(aP + 512);
        float4 a1y = *(const float4*)(aP + 528);
        bf16x8 bh0 = *(const bf16x8*)(bhP);
        bf16x8 bh1 = *(const bf16x8*)(bhP + 256);
        bf16x8 bl0 = *(const bf16x8*)(blP);
        bf16x8 bl1 = *(const bf16x8*)(blP + 256);
        if (do_stage) stage_A(bufn, s + 2, m0, w, lane, values);
        bf16x8 ah0, al0, ah1, al1;
        cvt_hilo(a0x, a0y, ah0, al0);
        cvt_hilo(a1x, a1y, ah1, al1);
        BARRIER();
        __builtin_amdgcn_s_setprio(1);
        MFMA3(ah0, al0, bh0, bl0, acc[0][0]);
        MFMA3(ah0, al0, bh1, bl1, acc[0][1]);
        MFMA3(ah1, al1, bh0, bl0, acc[1][0]);
        MFMA3(ah1, al1, bh1, bl1, acc[1][1]);
        __builtin_amdgcn_s_setprio(0);
        BARRIER();

        // ---------- phase 1: read B23, stage Bh(s+2), MFMA 01x23
        bf16x8 bh2 = *(const bf16x8*)(bhP + 512);
        bf16x8 bh3 = *(const bf16x8*)(bhP + 768);
        bf16x8 bl2 = *(const bf16x8*)(blP + 512);
        bf16x8 bl3 = *(const bf16x8*)(blP + 768);
        if (do_stage) stage_B(bufn, BH_OFF, s + 2, w, lane, W2Th);
        BARRIER();
        __builtin_amdgcn_s_setprio(1);
        MFMA3(ah0, al0, bh2, bl2, acc[0][2]);
        MFMA3(ah0, al0, bh3, bl3, acc[0][3]);
        MFMA3(ah1, al1, bh2, bl2, acc[1][2]);
        MFMA3(ah1, al1, bh3, bl3, acc[1][3]);
        __builtin_amdgcn_s_setprio(0);
        BARRIER();

        // ---------- phase 2: read A23, stage Bl(s+2), MFMA 23x01
        float4 a2x = *(const float4*)(aP + 1024);
        float4 a2y = *(const float4*)(aP + 1040);
        float4 a3x = *(const float4*)(aP + 1536);
        float4 a3y = *(const float4*)(aP + 1552);
        if (do_stage) stage_B(bufn, BL_OFF, s + 2, w, lane, W2Tl);
        bf16x8 ah2, al2, ah3, al3;
        cvt_hilo(a2x, a2y, ah2, al2);
        cvt_hilo(a3x, a3y, ah3, al3);
        BARRIER();
        __builtin_amdgcn_s_setprio(1);
        MFMA3(ah2, al2, bh0, bl0, acc[2][0]);
        MFMA3(ah2, al2, bh1, bl1, acc[2][1]);
        MFMA3(ah3, al3, bh0, bl0, acc[3][0]);
        MFMA3(ah3, al3, bh1, bl1, acc[3][1]);
        __builtin_amdgcn_s_setprio(0);
        BARRIER();

        // ---------- phase 3: MFMA 23x23, counted vmcnt for next step's buffer
        __builtin_amdgcn_s_setprio(1);
        MFMA3(ah2, al2, bh2, bl2, acc[2][2]);
        MFMA3(ah2, al2, bh3, bl3, acc[2][3]);
        MFMA3(ah3, al3, bh2, bl2, acc[3][2]);
        MFMA3(ah3, al3, bh3, bl3, acc[3][3]);
        __builtin_amdgcn_s_setprio(0);
        asm volatile("s_waitcnt vmcnt(6)" ::: "memory"); // buf[s+1] staged; s's 6 still in flight
        BARRIER();

        // ---------- nt-pass epilogue: fold acc into rowpart via tanh
        if ((s & 31) == 31) {
            int nt = s >> 5;
            #pragma unroll
            for (int ni = 0; ni < 4; ni++) {
                int n = nt * BN + wn * 64 + ni * 16 + c16;
                float qv = qp[b * N_ + n] + b2[n];
                float Vv = V[n];
                #pragma unroll
                for (int mi = 0; mi < 4; mi++)
                    #pragma unroll
                    for (int r = 0; r < 4; r++)
                        rowpart[mi * 4 + r] += tanhf(acc[mi][ni][r] + qv) * Vv;
            }
            #pragma unroll
            for (int mi = 0; mi < 4; mi++)
                #pragma unroll
                for (int ni = 0; ni < 4; ni++) {
                    f32x4 z = {0.f, 0.f, 0.f, 0.f};
                    acc[mi][ni] = z;
                }
        }
    }

    // final reduction: sum over the 16 n-lanes, then across the 4 wn waves via LDS
    #pragma unroll
    for (int i = 0; i < 16; i++) {
        float v = rowpart[i];
        v += __shfl_xor(v, 1);
        v += __shfl_xor(v, 2);
        v += __shfl_xor(v, 4);
        v += __shfl_xor(v, 8);
        rowpart[i] = v;
    }
    float* red = (float*)smem;  // 512 floats, aliases staging buffers (loop done)
    if (c16 == 0) {
        #pragma unroll
        for (int mi = 0; mi < 4; mi++)
            #pragma unroll
            for (int r = 0; r < 4; r++)
                red[wn * BM + wm * 64 + mi * 16 + g * 4 + r] = rowpart[mi * 4 + r];
    }
    BARRIER();
    if (tid < BM) {
        score[m0 + tid] = red[tid] + red[BM + tid] + red[2 * BM + tid] + red[3 * BM + tid] + bV[0];
    }
}

// K3: softmax over T per batch, in place
__global__ void k3_softmax(float* __restrict__ sw) {
    int b = blockIdx.x;
    float* row = sw + b * T_;
    int tid = threadIdx.x;
    float v[8];
    float lmax = -1e30f;
    #pragma unroll
    for (int i = 0; i < 8; i++) {
        v[i] = row[tid + i * 256];
        lmax = fmaxf(lmax, v[i]);
    }
    #pragma unroll
    for (int d = 1; d < 64; d <<= 1) lmax = fmaxf(lmax, __shfl_xor(lmax, d));
    __shared__ float sm[4], ss[4];
    if ((tid & 63) == 0) sm[tid >> 6] = lmax;
    __syncthreads();
    lmax = fmaxf(fmaxf(sm[0], sm[1]), fmaxf(sm[2], sm[3]));
    float lsum = 0.f;
    #pragma unroll
    for (int i = 0; i < 8; i++) {
        v[i] = expf(v[i] - lmax);
        lsum += v[i];
    }
    #pragma unroll
    for (int d = 1; d < 64; d <<= 1) lsum += __shfl_xor(lsum, d);
    if ((tid & 63) == 0) ss[tid >> 6] = lsum;
    __syncthreads();
    lsum = ss[0] + ss[1] + ss[2] + ss[3];
    float inv = 1.f / lsum;
    #pragma unroll
    for (int i = 0; i < 8; i++) row[tid + i * 256] = v[i] * inv;
}

// K4: context[b][d] += sum over this block's t-slice of w[b][t]*values[b][t][d]
__global__ void k4_context(const float* __restrict__ values,
                           const float* __restrict__ w,
                           float* __restrict__ ctx) {
    int b = blockIdx.x;
    int dc = blockIdx.y;           // 8 chunks of 128 d
    int tc = blockIdx.z;           // 8 chunks of 256 t
    int d4 = threadIdx.x & 31;     // float4 index within d-chunk
    int th = threadIdx.x >> 5;     // 8 t-slices of 32
    const float* wrow = w + b * T_;
    int d = dc * 128 + d4 * 4;
    const float* vbase = values + (size_t)b * T_ * D_ + d;
    float4 acc = {0.f, 0.f, 0.f, 0.f};
    int t0 = tc * 256 + th * 32;
    for (int t = t0; t < t0 + 32; t++) {
        float wt = wrow[t];
        float4 vv = *(const float4*)(vbase + (size_t)t * D_);
        acc.x += wt * vv.x;
        acc.y += wt * vv.y;
        acc.z += wt * vv.z;
        acc.w += wt * vv.w;
    }
    __shared__ float4 red4[256];
    red4[threadIdx.x] = acc;
    __syncthreads();
    if (th == 0) {
        float4 s = red4[d4];
        #pragma unroll
        for (int i = 1; i < 8; i++) {
            float4 o = red4[i * 32 + d4];
            s.x += o.x; s.y += o.y; s.z += o.z; s.w += o.w;
        }
        atomicAdd(&ctx[b * D_ + d + 0], s.x);
        atomicAdd(&ctx[b * D_ + d + 1], s.y);
        atomicAdd(&ctx[b * D_ + d + 2], s.z);
        atomicAdd(&ctx[b * D_ + d + 3], s.w);
    }
}

extern "C" void kernel_launch(void* const* d_in, const int* in_sizes, int n_in,
                              void* d_out, int out_size, void* d_ws, size_t ws_size,
                              hipStream_t stream) {
    const float* query  = (const float*)d_in[0];
    const float* values = (const float*)d_in[1];
    const float* W1     = (const float*)d_in[2];
    const float* b1     = (const float*)d_in[3];
    const float* W2     = (const float*)d_in[4];
    const float* b2     = (const float*)d_in[5];
    const float* V      = (const float*)d_in[6];
    const float* bV     = (const float*)d_in[7];

    float* ctx = (float*)d_out;                 // [B, D]
    float* weights = (float*)d_out + B_ * D_;   // [B, T]: scores, then softmax in place

    // ws: W2T_hi (2 MB) | W2T_lo (2 MB) | q_proj (128 KB)
    size_t need = (size_t)2 * N_ * D_ * sizeof(unsigned short) + (size_t)B_ * N_ * sizeof(float);
    if (ws_size < need) return;
    unsigned short* Th = (unsigned short*)d_ws;
    unsigned short* Tl = Th + (size_t)N_ * D_;
    float* qp = (float*)(Tl + (size_t)N_ * D_);

    static int attr_done = 0;
    (void)hipFuncSetAttribute((const void*)k2_score,
                              hipFuncAttributeMaxDynamicSharedMemorySize, SMEM_TOTAL);
    (void)attr_done;

    k0_w2t<<<dim3(N_ / 32, D_ / 32), 256, 0, stream>>>(W2, Th, Tl);
    k1_qproj<<<dim3(B_, N_ / 256), 256, 0, stream>>>(query, W1, b1, qp);
    k2_score<<<M_ / BM, 512, SMEM_TOTAL, stream>>>(values, Th, Tl, qp, b2, V, bV, weights);
    k3_softmax<<<B_, 256, 0, stream>>>(weights);
    hipMemsetAsync(ctx, 0, (size_t)B_ * D_ * sizeof(float), stream);
    k4_context<<<dim3(B_, 8, 8), 256, 0, stream>>>(values, weights, ctx);
}

// Round 4
// 598.811 us; speedup vs baseline: 1.2619x; 1.2619x over previous
//
#include <hip/hip_runtime.h>
#include <hip/hip_bf16.h>
#include <stdint.h>

#define B_ 32
#define T_ 2048
#define D_ 1024
#define N_ 1024
#define M_ (B_*T_)

// k2 geometry
#define BM 128
#define BN 256
#define BK 32
#define NSTEP 128          // 4 nt-passes * 32 k-steps
#define BUFBYTES 49152     // Af 16K (f32) + Bh 16K + Bl 16K
#define AF_OFF 0
#define BH_OFF 16384
#define BL_OFF 32768
#define SMEM_TOTAL (3 * BUFBYTES)

typedef short bf16x8 __attribute__((ext_vector_type(8)));
typedef float f32x4 __attribute__((ext_vector_type(4)));

__device__ __forceinline__ unsigned short bf16_rn(float x) {
    unsigned u = __float_as_uint(x);
    u += 0x7FFFu + ((u >> 16) & 1u);
    return (unsigned short)(u >> 16);
}

__device__ __forceinline__ void gload_lds16(const void* g, void* l) {
    __builtin_amdgcn_global_load_lds(
        (__attribute__((address_space(1))) void*)(g),
        (__attribute__((address_space(3))) void*)(l), 16, 0, 0);
}

#define FENCE() asm volatile("" ::: "memory")
#define BARRIER() do { FENCE(); __builtin_amdgcn_s_barrier(); FENCE(); } while (0)

// K0: W2 [D][N] fp32 -> W2T hi/lo bf16 [N][D]
__global__ void k0_w2t(const float* __restrict__ W2,
                       unsigned short* __restrict__ Th,
                       unsigned short* __restrict__ Tl) {
    __shared__ float tile[32][33];
    int n0 = blockIdx.x * 32, d0 = blockIdx.y * 32;
    int tx = threadIdx.x & 31, ty = threadIdx.x >> 5; // 32 x 8
    #pragma unroll
    for (int i = 0; i < 4; i++) {
        int d = d0 + ty + i * 8;
        tile[ty + i * 8][tx] = W2[d * N_ + n0 + tx];
    }
    __syncthreads();
    #pragma unroll
    for (int i = 0; i < 4; i++) {
        int n = n0 + ty + i * 8;
        float v = tile[tx][ty + i * 8];
        unsigned short h = bf16_rn(v);
        float hf = __uint_as_float((unsigned)h << 16);
        unsigned short l = bf16_rn(v - hf);
        Th[n * D_ + d0 + tx] = h;
        Tl[n * D_ + d0 + tx] = l;
    }
}

// K1: q_proj[b][n] = query[b]@W1[:,n] + b1[n]   (fp32)
__global__ void k1_qproj(const float* __restrict__ query,
                         const float* __restrict__ W1,
                         const float* __restrict__ b1,
                         float* __restrict__ qp) {
    int b = blockIdx.x;
    int n = blockIdx.y * 256 + threadIdx.x;
    const float* q = query + b * D_;
    const float* w = W1 + n;
    float s = 0.f;
    #pragma unroll 8
    for (int d = 0; d < D_; d++) s += q[d] * w[d * N_];
    qp[b * N_ + n] = s + b1[n];
}

// --- k2 staging (all LDS writes via global_load_lds; vmcnt-accounted)
// A tile fp32: semantic (g,row,half) at byte g*4096 + row*32 + half*16,
// XOR-swizzled: phys = sem ^ ((row&4)<<2). LDS dst linear; swizzle inverted
// in the SOURCE address (rule 21: linear dest + inverse-swz source + swz read).
__device__ __forceinline__ void stage_A(char* buf, int u, int m0, int w, int lane,
                                        const float* __restrict__ values) {
    const int k0 = (u & 31) * BK;
    #pragma unroll
    for (int i = 0; i < 2; i++) {
        int c = (w + i * 8) * 64 + lane;     // phys chunk 0..1023
        int g = c >> 8;
        int row = (c >> 1) & 127;
        int half = (c & 1) ^ ((row >> 2) & 1);
        const float* src = values + (size_t)(m0 + row) * D_ + k0 + g * 8 + half * 4;
        char* dst = buf + AF_OFF + (w + i * 8) * 1024;   // wave-uniform base
        gload_lds16(src, dst);
    }
}
// B tile: [g][256 rows][8 bf16], linear (conflict-free: 16B row stride)
__device__ __forceinline__ void stage_B(char* buf, int off, int u, int w, int lane,
                                        const unsigned short* __restrict__ W) {
    const int k0 = (u & 31) * BK;
    const int nt = u >> 5;
    #pragma unroll
    for (int i = 0; i < 2; i++) {
        int c = (w + i * 8) * 64 + lane;
        int g = c >> 8;
        int row = c & 255;
        const unsigned short* src = W + (size_t)(nt * BN + row) * D_ + k0 + g * 8;
        char* dst = buf + off + (w + i * 8) * 1024;
        gload_lds16(src, dst);
    }
}

__device__ __forceinline__ short bf16s(float f) {
    __hip_bfloat16 h = __float2bfloat16(f);   // RTN; compiler packs pairs (m240)
    return *reinterpret_cast<short*>(&h);
}
__device__ __forceinline__ bf16x8 cvt8(float4 x, float4 y) {
    bf16x8 r;
    r[0] = bf16s(x.x); r[1] = bf16s(x.y); r[2] = bf16s(x.z); r[3] = bf16s(x.w);
    r[4] = bf16s(y.x); r[5] = bf16s(y.y); r[6] = bf16s(y.z); r[7] = bf16s(y.w);
    return r;
}

#define MFMA2(a, bh, bl, A) do { \
    (A) = __builtin_amdgcn_mfma_f32_16x16x32_bf16((a), (bh), (A), 0, 0, 0); \
    (A) = __builtin_amdgcn_mfma_f32_16x16x32_bf16((a), (bl), (A), 0, 0, 0); \
} while (0)

// K2: fused score GEMM. A single bf16 (converted at read), B bf16 hi/lo
// (pre-split). 2 phases/step, 16 MFMA per barrier-pair, counted vmcnt.
__global__ __launch_bounds__(512, 2) void k2_score(
    const float* __restrict__ values,
    const unsigned short* __restrict__ W2Th,
    const unsigned short* __restrict__ W2Tl,
    const float* __restrict__ qp,
    const float* __restrict__ b2,
    const float* __restrict__ V,
    const float* __restrict__ bV,
    float* __restrict__ score) {
    extern __shared__ char smem[];

    const int tid = threadIdx.x;
    const int lane = tid & 63;
    const int w = tid >> 6;       // 0..7
    const int wm = w >> 2;        // 0..1  (M waves)
    const int wn = w & 3;         // 0..3  (N waves)
    const int c16 = lane & 15;
    const int g = lane >> 4;      // 0..3 k-group
    const int m0 = blockIdx.x * BM;
    const int b = m0 >> 11;       // m0 / T_
    const int xo = (c16 & 4) << 2; // A-read XOR swizzle term

    f32x4 acc[4][4];
    #pragma unroll
    for (int mi = 0; mi < 4; mi++)
        #pragma unroll
        for (int ni = 0; ni < 4; ni++) {
            f32x4 z = {0.f, 0.f, 0.f, 0.f};
            acc[mi][ni] = z;
        }
    float rowpart[16];
    #pragma unroll
    for (int i = 0; i < 16; i++) rowpart[i] = 0.f;

    // prologue: stage steps 0 and 1
    {
        char* b0 = smem;
        char* b1 = smem + BUFBYTES;
        stage_A(b0, 0, m0, w, lane, values);
        stage_B(b0, BH_OFF, 0, w, lane, W2Th);
        stage_B(b0, BL_OFF, 0, w, lane, W2Tl);
        stage_A(b1, 1, m0, w, lane, values);
        stage_B(b1, BH_OFF, 1, w, lane, W2Th);
        stage_B(b1, BL_OFF, 1, w, lane, W2Tl);
    }
    asm volatile("s_waitcnt vmcnt(6)" ::: "memory"); // buf0 landed
    BARRIER();

    for (int s = 0; s < NSTEP; ++s) {
        char* buf  = smem + (s % 3) * BUFBYTES;
        char* bufn = smem + ((s + 2) % 3) * BUFBYTES;
        const bool do_stage = (s + 2) < NSTEP;

        const char* aB  = buf + AF_OFF + g * 4096 + (wm * 64 + c16) * 32;
        const char* bhP = buf + BH_OFF + g * 4096 + (wn * 64 + c16) * 16;
        const char* blP = buf + BL_OFF + g * 4096 + (wn * 64 + c16) * 16;

        // ---------- phase 0: read A01 + all B; stage A,Bh(s+2); MFMA mi01 x ni0123
        float4 a0x = *(const float4*)(aB + xo);
        float4 a0y = *(const float4*)(aB + (16 ^ xo));
        float4 a1x = *(const float4*)(aB + 512 + xo);
        float4 a1y = *(const float4*)(aB + 512 + (16 ^ xo));
        bf16x8 bh[4], bl[4];
        #pragma unroll
        for (int ni = 0; ni < 4; ni++) {
            bh[ni] = *(const bf16x8*)(bhP + ni * 256);
            bl[ni] = *(const bf16x8*)(blP + ni * 256);
        }
        if (do_stage) {
            stage_A(bufn, s + 2, m0, w, lane, values);
            stage_B(bufn, BH_OFF, s + 2, w, lane, W2Th);
        }
        bf16x8 a0 = cvt8(a0x, a0y);
        bf16x8 a1 = cvt8(a1x, a1y);
        BARRIER();
        __builtin_amdgcn_s_setprio(1);
        #pragma unroll
        for (int ni = 0; ni < 4; ni++) MFMA2(a0, bh[ni], bl[ni], acc[0][ni]);
        #pragma unroll
        for (int ni = 0; ni < 4; ni++) MFMA2(a1, bh[ni], bl[ni], acc[1][ni]);
        __builtin_amdgcn_s_setprio(0);
        BARRIER();

        // ---------- phase 1: read A23; stage Bl(s+2); MFMA mi23 x ni0123
        float4 a2x = *(const float4*)(aB + 1024 + xo);
        float4 a2y = *(const float4*)(aB + 1024 + (16 ^ xo));
        float4 a3x = *(const float4*)(aB + 1536 + xo);
        float4 a3y = *(const float4*)(aB + 1536 + (16 ^ xo));
        if (do_stage) stage_B(bufn, BL_OFF, s + 2, w, lane, W2Tl);
        bf16x8 a2 = cvt8(a2x, a2y);
        bf16x8 a3 = cvt8(a3x, a3y);
        BARRIER();
        __builtin_amdgcn_s_setprio(1);
        #pragma unroll
        for (int ni = 0; ni < 4; ni++) MFMA2(a2, bh[ni], bl[ni], acc[2][ni]);
        #pragma unroll
        for (int ni = 0; ni < 4; ni++) MFMA2(a3, bh[ni], bl[ni], acc[3][ni]);
        __builtin_amdgcn_s_setprio(0);
        if (do_stage) {
            asm volatile("s_waitcnt vmcnt(6)" ::: "memory"); // (s+1)'s landed
        } else if (s + 1 < NSTEP) {
            asm volatile("s_waitcnt vmcnt(0)" ::: "memory"); // tail: drain fully
        }
        BARRIER();

        // ---------- nt-pass epilogue: fold acc into rowpart via tanh
        if ((s & 31) == 31) {
            int nt = s >> 5;
            #pragma unroll
            for (int ni = 0; ni < 4; ni++) {
                int n = nt * BN + wn * 64 + ni * 16 + c16;
                float qv = qp[b * N_ + n] + b2[n];
                float Vv = V[n];
                #pragma unroll
                for (int mi = 0; mi < 4; mi++)
                    #pragma unroll
                    for (int r = 0; r < 4; r++)
                        rowpart[mi * 4 + r] += tanhf(acc[mi][ni][r] + qv) * Vv;
            }
            #pragma unroll
            for (int mi = 0; mi < 4; mi++)
                #pragma unroll
                for (int ni = 0; ni < 4; ni++) {
                    f32x4 z = {0.f, 0.f, 0.f, 0.f};
                    acc[mi][ni] = z;
                }
        }
    }

    // final reduction: 16 n-lanes, then across the 4 wn waves via LDS
    #pragma unroll
    for (int i = 0; i < 16; i++) {
        float v = rowpart[i];
        v += __shfl_xor(v, 1);
        v += __shfl_xor(v, 2);
        v += __shfl_xor(v, 4);
        v += __shfl_xor(v, 8);
        rowpart[i] = v;
    }
    float* red = (float*)smem;  // aliases staging buffers (loop done)
    if (c16 == 0) {
        #pragma unroll
        for (int mi = 0; mi < 4; mi++)
            #pragma unroll
            for (int r = 0; r < 4; r++)
                red[wn * BM + wm * 64 + mi * 16 + g * 4 + r] = rowpart[mi * 4 + r];
    }
    BARRIER();
    if (tid < BM) {
        score[m0 + tid] = red[tid] + red[BM + tid] + red[2 * BM + tid] + red[3 * BM + tid] + bV[0];
    }
}

// K3: softmax over T per batch, in place
__global__ void k3_softmax(float* __restrict__ sw) {
    int b = blockIdx.x;
    float* row = sw + b * T_;
    int tid = threadIdx.x;
    float v[8];
    float lmax = -1e30f;
    #pragma unroll
    for (int i = 0; i < 8; i++) {
        v[i] = row[tid + i * 256];
        lmax = fmaxf(lmax, v[i]);
    }
    #pragma unroll
    for (int d = 1; d < 64; d <<= 1) lmax = fmaxf(lmax, __shfl_xor(lmax, d));
    __shared__ float sm[4], ss[4];
    if ((tid & 63) == 0) sm[tid >> 6] = lmax;
    __syncthreads();
    lmax = fmaxf(fmaxf(sm[0], sm[1]), fmaxf(sm[2], sm[3]));
    float lsum = 0.f;
    #pragma unroll
    for (int i = 0; i < 8; i++) {
        v[i] = expf(v[i] - lmax);
        lsum += v[i];
    }
    #pragma unroll
    for (int d = 1; d < 64; d <<= 1) lsum += __shfl_xor(lsum, d);
    if ((tid & 63) == 0) ss[tid >> 6] = lsum;
    __syncthreads();
    lsum = ss[0] + ss[1] + ss[2] + ss[3];
    float inv = 1.f / lsum;
    #pragma unroll
    for (int i = 0; i < 8; i++) row[tid + i * 256] = v[i] * inv;
}

// K4: context[b][d] += partial over t-slice (atomic, ctx pre-zeroed)
__global__ void k4_context(const float* __restrict__ values,
                           const float* __restrict__ w,
                           float* __restrict__ ctx) {
    int b = blockIdx.x;
    int dc = blockIdx.y;           // 8 chunks of 128 d
    int tc = blockIdx.z;           // 8 chunks of 256 t
    int d4 = threadIdx.x & 31;
    int th = threadIdx.x >> 5;     // 8 t-slices of 32
    const float* wrow = w + b * T_;
    int d = dc * 128 + d4 * 4;
    const float* vbase = values + (size_t)b * T_ * D_ + d;
    float4 acc = {0.f, 0.f, 0.f, 0.f};
    int t0 = tc * 256 + th * 32;
    for (int t = t0; t < t0 + 32; t++) {
        float wt = wrow[t];
        float4 vv = *(const float4*)(vbase + (size_t)t * D_);
        acc.x += wt * vv.x;
        acc.y += wt * vv.y;
        acc.z += wt * vv.z;
        acc.w += wt * vv.w;
    }
    __shared__ float4 red4[256];
    red4[threadIdx.x] = acc;
    __syncthreads();
    if (th == 0) {
        float4 s = red4[d4];
        #pragma unroll
        for (int i = 1; i < 8; i++) {
            float4 o = red4[i * 32 + d4];
            s.x += o.x; s.y += o.y; s.z += o.z; s.w += o.w;
        }
        atomicAdd(&ctx[b * D_ + d + 0], s.x);
        atomicAdd(&ctx[b * D_ + d + 1], s.y);
        atomicAdd(&ctx[b * D_ + d + 2], s.z);
        atomicAdd(&ctx[b * D_ + d + 3], s.w);
    }
}

extern "C" void kernel_launch(void* const* d_in, const int* in_sizes, int n_in,
                              void* d_out, int out_size, void* d_ws, size_t ws_size,
                              hipStream_t stream) {
    const float* query  = (const float*)d_in[0];
    const float* values = (const float*)d_in[1];
    const float* W1     = (const float*)d_in[2];
    const float* b1     = (const float*)d_in[3];
    const float* W2     = (const float*)d_in[4];
    const float* b2     = (const float*)d_in[5];
    const float* V      = (const float*)d_in[6];
    const float* bV     = (const float*)d_in[7];

    float* ctx = (float*)d_out;                 // [B, D]
    float* weights = (float*)d_out + B_ * D_;   // [B, T]: scores, then softmax in place

    // ws: W2T_hi (2 MB) | W2T_lo (2 MB) | q_proj (128 KB)
    size_t need = (size_t)2 * N_ * D_ * sizeof(unsigned short) + (size_t)B_ * N_ * sizeof(float);
    if (ws_size < need) return;
    unsigned short* Th = (unsigned short*)d_ws;
    unsigned short* Tl = Th + (size_t)N_ * D_;
    float* qp = (float*)(Tl + (size_t)N_ * D_);

    (void)hipFuncSetAttribute((const void*)k2_score,
                              hipFuncAttributeMaxDynamicSharedMemorySize, SMEM_TOTAL);

    k0_w2t<<<dim3(N_ / 32, D_ / 32), 256, 0, stream>>>(W2, Th, Tl);
    k1_qproj<<<dim3(B_, N_ / 256), 256, 0, stream>>>(query, W1, b1, qp);
    k2_score<<<M_ / BM, 512, SMEM_TOTAL, stream>>>(values, Th, Tl, qp, b2, V, bV, weights);
    k3_softmax<<<B_, 256, 0, stream>>>(weights);
    hipMemsetAsync(ctx, 0, (size_t)B_ * D_ * sizeof(float), stream);
    k4_context<<<dim3(B_, 8, 8), 256, 0, stream>>>(values, weights, ctx);
}